// Round 11
// baseline (261.127 us; speedup 1.0000x reference)
//
#include <hip/hip_runtime.h>

#define N_NODES 20000
#define N_EDGES 320000
#define IN_F    168
#define HID     256
#define K1P     192   // GEMM-1 K (IN_F zero-padded to multiple of 64)
#define RS      256   // padded row stride (shorts) for gather sources

typedef __attribute__((ext_vector_type(8))) short bf16x8;
typedef __attribute__((ext_vector_type(4))) float f32x4;

__device__ __forceinline__ short f2bf(float f) {
    union { float f; unsigned u; } v; v.f = f;
    unsigned r = v.u + 0x7FFFu + ((v.u >> 16) & 1u);
    return (short)(r >> 16);
}
__device__ __forceinline__ float bf2f(short s) {
    union { unsigned u; float f; } v; v.u = ((unsigned)(unsigned short)s) << 16;
    return v.f;
}

// ---------------- fused prep: x->bf16 (256-padded), W splits, edge deg/count ----
// blocks [0,20000): x rows -> xb[20000][256] (cols 168..255 zero)
// blocks [20000,20256): W1 rows (192-padded split)
// blocks [20256,20512): W2 rows (split)
// blocks [20512,21762): edge deg/count atomics

__global__ void prep_all(const float* __restrict__ x, short* __restrict__ xb,
                         const float* __restrict__ W1, const float* __restrict__ W2,
                         short* __restrict__ w1h, short* __restrict__ w1l,
                         short* __restrict__ w2h, short* __restrict__ w2l,
                         const int* __restrict__ ei, const float* __restrict__ ew,
                         float* __restrict__ deg, int* __restrict__ counts) {
    int b = blockIdx.x;
    int k = threadIdx.x;
    if (b < N_NODES) {
        float v = (k < IN_F) ? x[(size_t)b * IN_F + k] : 0.f;
        xb[(size_t)b * RS + k] = f2bf(v);
        return;
    }
    b -= N_NODES;
    if (b < 256) {
        if (k >= K1P) return;
        float v = (k < IN_F) ? W1[(size_t)b * IN_F + k] : 0.f;
        short h = f2bf(v);
        w1h[(size_t)b * K1P + k] = h;
        w1l[(size_t)b * K1P + k] = f2bf(v - bf2f(h));
        return;
    }
    if (b < 512) {
        int r = b - 256;
        float v = W2[(size_t)r * HID + k];
        short h = f2bf(v);
        w2h[(size_t)r * HID + k] = h;
        w2l[(size_t)r * HID + k] = f2bf(v - bf2f(h));
        return;
    }
    int e = (b - 512) * 256 + k;
    if (e < N_EDGES) {
        int d = ei[N_EDGES + e];
        atomicAdd(&deg[d], ew[e]);
        atomicAdd(&counts[d], 1);
    }
}

// ---------------- scan (2-kernel) + scatter ----------------

__global__ __launch_bounds__(1024) void scan_part(const int* __restrict__ counts,
                                                  int* __restrict__ offs,
                                                  int* __restrict__ bsum,
                                                  float* __restrict__ deg, int n) {
    int tid  = threadIdx.x;
    int lane = tid & 63;
    int wv   = tid >> 6;
    int i = blockIdx.x * 1024 + tid;
    if (i < n) deg[i] = rsqrtf(deg[i] + 1.0f);     // self-loop weight 1.0
    __shared__ int wsum[16];
    int v = (i < n) ? counts[i] : 0;
    int incl = v;
    #pragma unroll
    for (int d = 1; d < 64; d <<= 1) {
        int t = __shfl_up(incl, d);
        if (lane >= d) incl += t;
    }
    if (lane == 63) wsum[wv] = incl;
    __syncthreads();
    if (wv == 0) {
        int w = (lane < 16) ? wsum[lane] : 0;
        int winc = w;
        #pragma unroll
        for (int d = 1; d < 16; d <<= 1) {
            int t = __shfl_up(winc, d);
            if (lane >= d) winc += t;
        }
        if (lane < 16) wsum[lane] = winc - w;
    }
    __syncthreads();
    if (i < n) offs[i] = wsum[wv] + incl - v;
    if (tid == 1023) bsum[blockIdx.x] = wsum[15] + incl;
}

__global__ __launch_bounds__(1024) void scan_add(const int* __restrict__ bsum,
                                                 int* __restrict__ offs, int n) {
    int i = blockIdx.x * 1024 + threadIdx.x;
    int add = 0;
    for (int b = 0; b < (int)blockIdx.x; ++b) add += bsum[b];
    if (i < n) offs[i] += add;
    if (i == n) offs[n] = add + bsum[blockIdx.x];
}

__global__ void scatter_edges(const int* __restrict__ ei, const float* __restrict__ ew,
                              const float* __restrict__ dinv, const int* __restrict__ offs,
                              int* __restrict__ cursor, int* __restrict__ csr_src,
                              float* __restrict__ csr_norm) {
    int e = blockIdx.x * blockDim.x + threadIdx.x;
    if (e >= N_EDGES) return;
    int s = ei[e];
    int d = ei[N_EDGES + e];
    int pos = offs[d] + atomicAdd(&cursor[d], 1);
    csr_src[pos]  = s;
    csr_norm[pos] = dinv[s] * ew[e] * dinv[d];
}

// ---------------- multi-pass gather (Agg; emits split-bf16 A operand) ----------
// Feature dim chunked into 64-feature (128B, line-aligned) passes; pass pinned
// to an XCD pair via RR heuristic (xcd = blockIdx & 7, pass = xcd>>1): per XCD
// the pass slice is 2.56 MB -> L2-resident -> ~8x line reuse.
// rows: bf16, stride RS=256. out: split bf16, stride out_stride.
// npasses=3 (agg_x: features 0..191) or 4 (agg_h: 0..255).

__global__ __launch_bounds__(256) void agg_pass(const short* __restrict__ rows,
                                                const float* __restrict__ dinv,
                                                const int* __restrict__ offs,
                                                const int* __restrict__ csr_src,
                                                const float* __restrict__ csr_norm,
                                                short* __restrict__ outh,
                                                short* __restrict__ outl,
                                                int out_stride, int npasses) {
    const int b    = blockIdx.x;           // grid = 2500 * 8
    const int xcd  = b & 7;
    const int pass = xcd >> 1;
    if (pass >= npasses) return;
    const int half = xcd & 1;
    const int j    = b >> 3;               // 0..2499
    const int wave = threadIdx.x >> 6;
    const int lane = threadIdx.x & 63;
    const int n    = (half * 2500 + j) * 4 + wave;   // covers [0,20000)
    const int fo   = pass * 64;

    float di = dinv[n];
    float acc = di * di * bf2f(rows[(size_t)n * RS + fo + lane]);

    int p0 = offs[n], p1 = offs[n + 1];
    int p = p0;
    for (; p + 8 <= p1; p += 8) {
        int s[8]; float w[8]; short r[8];
        #pragma unroll
        for (int i = 0; i < 8; ++i) { s[i] = csr_src[p + i]; w[i] = csr_norm[p + i]; }
        #pragma unroll
        for (int i = 0; i < 8; ++i) r[i] = rows[(size_t)s[i] * RS + fo + lane];
        #pragma unroll
        for (int i = 0; i < 8; ++i) acc += w[i] * bf2f(r[i]);
    }
    for (; p + 4 <= p1; p += 4) {
        int s[4]; float w[4]; short r[4];
        #pragma unroll
        for (int i = 0; i < 4; ++i) { s[i] = csr_src[p + i]; w[i] = csr_norm[p + i]; }
        #pragma unroll
        for (int i = 0; i < 4; ++i) r[i] = rows[(size_t)s[i] * RS + fo + lane];
        #pragma unroll
        for (int i = 0; i < 4; ++i) acc += w[i] * bf2f(r[i]);
    }
    for (; p < p1; ++p) {
        int   s0 = csr_src[p];
        float w0 = csr_norm[p];
        acc += w0 * bf2f(rows[(size_t)s0 * RS + fo + lane]);
    }

    short h = f2bf(acc);
    short l = f2bf(acc - bf2f(h));
    size_t ob = (size_t)n * out_stride + fo + lane;
    outh[ob] = h;
    outl[ob] = l;
}

// ---------------- MFMA GEMM with fused bias+ReLU epilogue ----------------
// C[M,256] = relu(A[M,K] * W[256,K]^T + bias). Split-bf16 3-product.
// 64x64 tile, 4 waves each 32x32 (2x2 MFMA 16x16x32), BK=64, LDS-staged,
// register prefetch, XCD-affinity swizzle (4 nt-siblings share an XCD's L2).
// mode 0: store bf16-hi to Cbf; mode 1: store fp32 to Cf.

#define LDS_STRIDE 72

__global__ __launch_bounds__(256) void gemm_split(const short* __restrict__ Ah,
                                                  const short* __restrict__ Al,
                                                  const short* __restrict__ Wh,
                                                  const short* __restrict__ Wl,
                                                  const float* __restrict__ bias,
                                                  float* __restrict__ Cf,
                                                  short* __restrict__ Cbf,
                                                  int M, int Ks, int nsteps, int mode) {
    __shared__ short sAh[64 * LDS_STRIDE];
    __shared__ short sAl[64 * LDS_STRIDE];
    __shared__ short sWh[64 * LDS_STRIDE];
    __shared__ short sWl[64 * LDS_STRIDE];

    // swizzle: idx = group*32 + slot*8 + xcd  ->  mt = group*8 + xcd, nt = slot
    const int idx   = blockIdx.x;
    const int group = idx >> 5;
    const int xcd   = idx & 7;
    const int slot  = (idx >> 3) & 3;
    const int mt    = group * 8 + xcd;
    const int mtiles = (M + 63) >> 6;
    if (mt >= mtiles) return;
    const int bm = mt * 64;
    const int bn = slot * 64;

    const int tid  = threadIdx.x;
    const int lane = tid & 63;
    const int wv   = tid >> 6;
    const int l16  = lane & 15;
    const int quad = lane >> 4;
    const int wm   = (wv & 1) * 32;
    const int wn   = (wv >> 1) * 32;

    const int srow = tid >> 2;
    const int sseg = (tid & 3) * 16;
    int arow = bm + srow; if (arow >= M) arow = M - 1;
    const short* gAh = Ah + (size_t)arow * Ks;
    const short* gAl = Al + (size_t)arow * Ks;
    const short* gWh = Wh + (size_t)(bn + srow) * Ks;
    const short* gWl = Wl + (size_t)(bn + srow) * Ks;
    const int lds_off = srow * LDS_STRIDE + sseg;

    f32x4 acc00 = {0,0,0,0}, acc01 = {0,0,0,0}, acc10 = {0,0,0,0}, acc11 = {0,0,0,0};

    int4 pah0 = *(const int4*)(gAh + sseg), pah1 = *(const int4*)(gAh + sseg + 8);
    int4 pal0 = *(const int4*)(gAl + sseg), pal1 = *(const int4*)(gAl + sseg + 8);
    int4 pwh0 = *(const int4*)(gWh + sseg), pwh1 = *(const int4*)(gWh + sseg + 8);
    int4 pwl0 = *(const int4*)(gWl + sseg), pwl1 = *(const int4*)(gWl + sseg + 8);

    for (int ks = 0; ks < nsteps; ++ks) {
        *(int4*)&sAh[lds_off] = pah0; *(int4*)&sAh[lds_off + 8] = pah1;
        *(int4*)&sAl[lds_off] = pal0; *(int4*)&sAl[lds_off + 8] = pal1;
        *(int4*)&sWh[lds_off] = pwh0; *(int4*)&sWh[lds_off + 8] = pwh1;
        *(int4*)&sWl[lds_off] = pwl0; *(int4*)&sWl[lds_off + 8] = pwl1;
        __syncthreads();
        if (ks + 1 < nsteps) {
            int o = (ks + 1) * 64 + sseg;
            pah0 = *(const int4*)(gAh + o); pah1 = *(const int4*)(gAh + o + 8);
            pal0 = *(const int4*)(gAl + o); pal1 = *(const int4*)(gAl + o + 8);
            pwh0 = *(const int4*)(gWh + o); pwh1 = *(const int4*)(gWh + o + 8);
            pwl0 = *(const int4*)(gWl + o); pwl1 = *(const int4*)(gWl + o + 8);
        }
        #pragma unroll
        for (int o = 0; o < 2; ++o) {
            const int a0 = (wm + l16) * LDS_STRIDE + o * 32 + quad * 8;
            const int a1 = a0 + 16 * LDS_STRIDE;
            const int w0 = (wn + l16) * LDS_STRIDE + o * 32 + quad * 8;
            const int w1 = w0 + 16 * LDS_STRIDE;
            bf16x8 ah0 = *(const bf16x8*)&sAh[a0];
            bf16x8 ah1 = *(const bf16x8*)&sAh[a1];
            bf16x8 al0 = *(const bf16x8*)&sAl[a0];
            bf16x8 al1 = *(const bf16x8*)&sAl[a1];
            bf16x8 wh0 = *(const bf16x8*)&sWh[w0];
            bf16x8 wh1 = *(const bf16x8*)&sWh[w1];
            bf16x8 wl0 = *(const bf16x8*)&sWl[w0];
            bf16x8 wl1 = *(const bf16x8*)&sWl[w1];
            acc00 = __builtin_amdgcn_mfma_f32_16x16x32_bf16(ah0, wh0, acc00, 0, 0, 0);
            acc00 = __builtin_amdgcn_mfma_f32_16x16x32_bf16(ah0, wl0, acc00, 0, 0, 0);
            acc00 = __builtin_amdgcn_mfma_f32_16x16x32_bf16(al0, wh0, acc00, 0, 0, 0);
            acc01 = __builtin_amdgcn_mfma_f32_16x16x32_bf16(ah0, wh1, acc01, 0, 0, 0);
            acc01 = __builtin_amdgcn_mfma_f32_16x16x32_bf16(ah0, wl1, acc01, 0, 0, 0);
            acc01 = __builtin_amdgcn_mfma_f32_16x16x32_bf16(al0, wh1, acc01, 0, 0, 0);
            acc10 = __builtin_amdgcn_mfma_f32_16x16x32_bf16(ah1, wh0, acc10, 0, 0, 0);
            acc10 = __builtin_amdgcn_mfma_f32_16x16x32_bf16(ah1, wl0, acc10, 0, 0, 0);
            acc10 = __builtin_amdgcn_mfma_f32_16x16x32_bf16(al1, wh0, acc10, 0, 0, 0);
            acc11 = __builtin_amdgcn_mfma_f32_16x16x32_bf16(ah1, wh1, acc11, 0, 0, 0);
            acc11 = __builtin_amdgcn_mfma_f32_16x16x32_bf16(ah1, wl1, acc11, 0, 0, 0);
            acc11 = __builtin_amdgcn_mfma_f32_16x16x32_bf16(al1, wh1, acc11, 0, 0, 0);
        }
        __syncthreads();
    }

    const int colb = bn + wn + l16;
    const int rowb = bm + wm + quad * 4;
    const float b0 = bias[colb];
    const float b1 = bias[colb + 16];
    #pragma unroll
    for (int r = 0; r < 4; ++r) {
        int row = rowb + r;
        if (row < M) {
            float v0 = acc00[r] + b0; v0 = v0 > 0.f ? v0 : 0.f;
            float v1 = acc01[r] + b1; v1 = v1 > 0.f ? v1 : 0.f;
            if (mode == 0) {
                Cbf[(size_t)row * HID + colb]      = f2bf(v0);
                Cbf[(size_t)row * HID + colb + 16] = f2bf(v1);
            } else {
                Cf[(size_t)row * HID + colb]      = v0;
                Cf[(size_t)row * HID + colb + 16] = v1;
            }
        }
        int row2 = row + 16;
        if (row2 < M) {
            float v0 = acc10[r] + b0; v0 = v0 > 0.f ? v0 : 0.f;
            float v1 = acc11[r] + b1; v1 = v1 > 0.f ? v1 : 0.f;
            if (mode == 0) {
                Cbf[(size_t)row2 * HID + colb]      = f2bf(v0);
                Cbf[(size_t)row2 * HID + colb + 16] = f2bf(v1);
            } else {
                Cf[(size_t)row2 * HID + colb]      = v0;
                Cf[(size_t)row2 * HID + colb + 16] = v1;
            }
        }
    }
}

// ---------------- launch ----------------

extern "C" void kernel_launch(void* const* d_in, const int* in_sizes, int n_in,
                              void* d_out, int out_size, void* d_ws, size_t ws_size,
                              hipStream_t stream) {
    const float* x  = (const float*)d_in[0];
    const int*   ei = (const int*)d_in[1];
    const float* ew = (const float*)d_in[2];
    const float* W1 = (const float*)d_in[3];
    const float* b1 = (const float*)d_in[4];
    const float* W2 = (const float*)d_in[5];
    const float* b2 = (const float*)d_in[6];
    float* out = (float*)d_out;

    char* ws = (char*)d_ws;
    float* deg      = (float*)(ws);                 // 20000 f32 (becomes dinv)
    int*   counts   = (int*)(ws + 80000);           // 20000 i32
    int*   cursor   = (int*)(ws + 160000);          // 20000 i32
    int*   offs     = (int*)(ws + 240000);          // 20001 i32
    int*   bsum     = (int*)(ws + 320016);          // 20 i32 (pad to 320144)
    int*   csr_src  = (int*)(ws + 320144);          // 320000 i32 -> 1600144
    float* csr_norm = (float*)(ws + 1600144);       // 320000 f32 -> 2880144
    // region A: agg_x split (2 x 20000x192 bf16 = 15.36MB), dead after gemm1;
    // reused for agg_h split (2 x 20000x256 bf16 = 20.48MB)
    short* axh      = (short*)(ws + 2880144);       // -> 10560144
    short* axl      = (short*)(ws + 10560144);      // -> 18240144
    short* ahh      = (short*)(ws + 2880144);       // -> 13120144
    short* ahl      = (short*)(ws + 13120144);      // -> 23360144
    short* h1h      = (short*)(ws + 23360144);      // 20000x256 bf16 -> 33600144
    short* w1h      = (short*)(ws + 33600144);      // 256x192 -> 33698448
    short* w1l      = (short*)(ws + 33698448);      // -> 33796752
    short* w2h      = (short*)(ws + 33796752);      // 256x256 -> 33927824
    short* w2l      = (short*)(ws + 33927824);      // -> 34058896
    short* xb       = (short*)(ws + 34058896);      // 20000x256 bf16 -> 44298896

    hipMemsetAsync(d_ws, 0, 240000, stream);        // deg, counts, cursor

    const int TB = 256;
    prep_all<<<N_NODES + 512 + (N_EDGES + 255) / 256, 256, 0, stream>>>(
        x, xb, W1, W2, w1h, w1l, w2h, w2l, ei, ew, deg, counts);
    scan_part<<<20, 1024, 0, stream>>>(counts, offs, bsum, deg, N_NODES);
    scan_add<<<20, 1024, 0, stream>>>(bsum, offs, N_NODES);
    scatter_edges<<<(N_EDGES + TB - 1) / TB, TB, 0, stream>>>(ei, ew, deg, offs, cursor,
                                                              csr_src, csr_norm);

    const int mtiles = (N_NODES + 63) / 64;          // 313
    const int gemm_grid = ((mtiles + 7) / 8) * 32;   // 1280
    const int agg_grid = 2500 * 8;                   // nodes x passes, XCD-pinned
    // layer 1: Agg(bf16 xb) -> split (3 passes); GEMM(+b1, ReLU) -> h1 bf16-hi
    agg_pass<<<agg_grid, 256, 0, stream>>>(xb, deg, offs, csr_src, csr_norm,
                                           axh, axl, K1P, 3);
    gemm_split<<<gemm_grid, 256, 0, stream>>>(axh, axl, w1h, w1l, b1, nullptr, h1h,
                                              N_NODES, K1P, 3, 0);
    // layer 2: Agg(bf16 h1) -> split (4 passes); GEMM(+b2, ReLU) -> out fp32
    agg_pass<<<agg_grid, 256, 0, stream>>>(h1h, deg, offs, csr_src, csr_norm,
                                           ahh, ahl, HID, 4);
    gemm_split<<<gemm_grid, 256, 0, stream>>>(ahh, ahl, w2h, w2l, b2, out, nullptr,
                                              N_NODES, HID, 4, 1);
}

// Round 12
// 220.025 us; speedup vs baseline: 1.1868x; 1.1868x over previous
//
#include <hip/hip_runtime.h>

#define N_NODES 20000
#define N_EDGES 320000
#define IN_F    168
#define HID     256
#define K1P     192   // GEMM-1 K (IN_F zero-padded to multiple of 64)
#define XS      192   // xb row stride in shorts (384B, 128B-aligned)
#define NF4     42    // IN_F / 4

typedef __attribute__((ext_vector_type(8))) short bf16x8;
typedef __attribute__((ext_vector_type(4))) float f32x4;

__device__ __forceinline__ short f2bf(float f) {
    union { float f; unsigned u; } v; v.f = f;
    unsigned r = v.u + 0x7FFFu + ((v.u >> 16) & 1u);
    return (short)(r >> 16);
}
__device__ __forceinline__ float bf2f(short s) {
    union { unsigned u; float f; } v; v.u = ((unsigned)(unsigned short)s) << 16;
    return v.f;
}

// ---------------- fused prep: x->bf16 (192-padded), W splits, edge deg/count ----
// blocks [0,20000): x rows -> xb[20000][192] (cols 168..191 zero)
// blocks [20000,20256): W1 rows (192-padded split)
// blocks [20256,20512): W2 rows (split)
// blocks [20512,...): edge deg/count atomics

__global__ void prep_all(const float* __restrict__ x, short* __restrict__ xb,
                         const float* __restrict__ W1, const float* __restrict__ W2,
                         short* __restrict__ w1h, short* __restrict__ w1l,
                         short* __restrict__ w2h, short* __restrict__ w2l,
                         const int* __restrict__ ei, const float* __restrict__ ew,
                         float* __restrict__ deg, int* __restrict__ counts) {
    int b = blockIdx.x;
    int k = threadIdx.x;
    if (b < N_NODES) {
        if (k >= XS) return;
        float v = (k < IN_F) ? x[(size_t)b * IN_F + k] : 0.f;
        xb[(size_t)b * XS + k] = f2bf(v);
        return;
    }
    b -= N_NODES;
    if (b < 256) {
        if (k >= K1P) return;
        float v = (k < IN_F) ? W1[(size_t)b * IN_F + k] : 0.f;
        short h = f2bf(v);
        w1h[(size_t)b * K1P + k] = h;
        w1l[(size_t)b * K1P + k] = f2bf(v - bf2f(h));
        return;
    }
    if (b < 512) {
        int r = b - 256;
        float v = W2[(size_t)r * HID + k];
        short h = f2bf(v);
        w2h[(size_t)r * HID + k] = h;
        w2l[(size_t)r * HID + k] = f2bf(v - bf2f(h));
        return;
    }
    int e = (b - 512) * 256 + k;
    if (e < N_EDGES) {
        int d = ei[N_EDGES + e];
        atomicAdd(&deg[d], ew[e]);
        atomicAdd(&counts[d], 1);
    }
}

// ---------------- scan (2-kernel) + scatter ----------------

__global__ __launch_bounds__(1024) void scan_part(const int* __restrict__ counts,
                                                  int* __restrict__ offs,
                                                  int* __restrict__ bsum,
                                                  float* __restrict__ deg, int n) {
    int tid  = threadIdx.x;
    int lane = tid & 63;
    int wv   = tid >> 6;
    int i = blockIdx.x * 1024 + tid;
    if (i < n) deg[i] = rsqrtf(deg[i] + 1.0f);     // self-loop weight 1.0
    __shared__ int wsum[16];
    int v = (i < n) ? counts[i] : 0;
    int incl = v;
    #pragma unroll
    for (int d = 1; d < 64; d <<= 1) {
        int t = __shfl_up(incl, d);
        if (lane >= d) incl += t;
    }
    if (lane == 63) wsum[wv] = incl;
    __syncthreads();
    if (wv == 0) {
        int w = (lane < 16) ? wsum[lane] : 0;
        int winc = w;
        #pragma unroll
        for (int d = 1; d < 16; d <<= 1) {
            int t = __shfl_up(winc, d);
            if (lane >= d) winc += t;
        }
        if (lane < 16) wsum[lane] = winc - w;
    }
    __syncthreads();
    if (i < n) offs[i] = wsum[wv] + incl - v;
    if (tid == 1023) bsum[blockIdx.x] = wsum[15] + incl;
}

__global__ __launch_bounds__(1024) void scan_add(const int* __restrict__ bsum,
                                                 int* __restrict__ offs, int n) {
    int i = blockIdx.x * 1024 + threadIdx.x;
    int add = 0;
    for (int b = 0; b < (int)blockIdx.x; ++b) add += bsum[b];
    if (i < n) offs[i] += add;
    if (i == n) offs[n] = add + bsum[blockIdx.x];
}

// packed edge record: .x = src node, .y = norm as float bits
__global__ void scatter_edges(const int* __restrict__ ei, const float* __restrict__ ew,
                              const float* __restrict__ dinv, const int* __restrict__ offs,
                              int* __restrict__ cursor, int2* __restrict__ er) {
    int e = blockIdx.x * blockDim.x + threadIdx.x;
    if (e >= N_EDGES) return;
    int s = ei[e];
    int d = ei[N_EDGES + e];
    int pos = offs[d] + atomicAdd(&cursor[d], 1);
    float nm = dinv[s] * ew[e] * dinv[d];
    er[pos] = make_int2(s, __float_as_int(nm));
}

// ---------------- gathers (Agg BEFORE GEMM; emit split-bf16 A operand) ----------

// layer 1: agg from bf16 xb rows (384B stride, 336B data); lanes 0..41 own short4.
__global__ __launch_bounds__(256) void agg_x_split(const short* __restrict__ xb,
                                                   const float* __restrict__ dinv,
                                                   const int* __restrict__ offs,
                                                   const int2* __restrict__ er,
                                                   short* __restrict__ axh,
                                                   short* __restrict__ axl) {
    int wave = threadIdx.x >> 6;
    int lane = threadIdx.x & 63;
    int n = blockIdx.x * 4 + wave;
    bool act = lane < NF4;
    int lo4 = act ? lane * 4 : 0;                  // inactive lanes read row start (safe)
    float di = dinv[n];
    float sw = di * di;
    short4 sv = *(const short4*)(xb + (size_t)n * XS + lo4);
    float ax = sw * bf2f(sv.x), ay = sw * bf2f(sv.y);
    float az = sw * bf2f(sv.z), aw = sw * bf2f(sv.w);

    int p0 = offs[n], p1 = offs[n + 1];
    int p = p0;
    for (; p + 8 <= p1; p += 8) {
        int2 e[8]; short4 r[8];
        #pragma unroll
        for (int j = 0; j < 8; ++j) e[j] = er[p + j];
        #pragma unroll
        for (int j = 0; j < 8; ++j) r[j] = *(const short4*)(xb + (size_t)e[j].x * XS + lo4);
        #pragma unroll
        for (int j = 0; j < 8; ++j) {
            float w = __int_as_float(e[j].y);
            ax += w * bf2f(r[j].x); ay += w * bf2f(r[j].y);
            az += w * bf2f(r[j].z); aw += w * bf2f(r[j].w);
        }
    }
    for (; p + 4 <= p1; p += 4) {
        int2 e[4]; short4 r[4];
        #pragma unroll
        for (int j = 0; j < 4; ++j) e[j] = er[p + j];
        #pragma unroll
        for (int j = 0; j < 4; ++j) r[j] = *(const short4*)(xb + (size_t)e[j].x * XS + lo4);
        #pragma unroll
        for (int j = 0; j < 4; ++j) {
            float w = __int_as_float(e[j].y);
            ax += w * bf2f(r[j].x); ay += w * bf2f(r[j].y);
            az += w * bf2f(r[j].z); aw += w * bf2f(r[j].w);
        }
    }
    for (; p < p1; ++p) {
        int2 e0 = er[p];
        float w0 = __int_as_float(e0.y);
        short4 r0 = *(const short4*)(xb + (size_t)e0.x * XS + lo4);
        ax += w0 * bf2f(r0.x); ay += w0 * bf2f(r0.y);
        az += w0 * bf2f(r0.z); aw += w0 * bf2f(r0.w);
    }

    size_t base = (size_t)n * K1P + lane * 4;
    if (act) {
        float a[4] = {ax, ay, az, aw};
        short hv[4], lv[4];
        #pragma unroll
        for (int i = 0; i < 4; ++i) {
            hv[i] = f2bf(a[i]);
            lv[i] = f2bf(a[i] - bf2f(hv[i]));
        }
        *(short4*)&axh[base] = make_short4(hv[0], hv[1], hv[2], hv[3]);
        *(short4*)&axl[base] = make_short4(lv[0], lv[1], lv[2], lv[3]);
    } else if (lane < 48) {                        // zero pad cols 168..191
        short4 z = make_short4(0, 0, 0, 0);
        *(short4*)&axh[base] = z;
        *(short4*)&axl[base] = z;
    }
}

// layer 2: agg from bf16 h1 rows (512B); one short4 per lane; 8-deep ILP.
__global__ __launch_bounds__(256) void agg_h_split(const short* __restrict__ h1h,
                                                   const float* __restrict__ dinv,
                                                   const int* __restrict__ offs,
                                                   const int2* __restrict__ er,
                                                   short* __restrict__ ahh,
                                                   short* __restrict__ ahl) {
    int wave = threadIdx.x >> 6;
    int lane = threadIdx.x & 63;
    int n = blockIdx.x * 4 + wave;
    int lo4 = lane * 4;
    float di = dinv[n];
    float sw = di * di;
    short4 sv = *(const short4*)(h1h + (size_t)n * HID + lo4);
    float ax = sw * bf2f(sv.x), ay = sw * bf2f(sv.y);
    float az = sw * bf2f(sv.z), aw = sw * bf2f(sv.w);

    int p0 = offs[n], p1 = offs[n + 1];
    int p = p0;
    for (; p + 8 <= p1; p += 8) {
        int2 e[8]; short4 r[8];
        #pragma unroll
        for (int j = 0; j < 8; ++j) e[j] = er[p + j];
        #pragma unroll
        for (int j = 0; j < 8; ++j) r[j] = *(const short4*)(h1h + (size_t)e[j].x * HID + lo4);
        #pragma unroll
        for (int j = 0; j < 8; ++j) {
            float w = __int_as_float(e[j].y);
            ax += w * bf2f(r[j].x); ay += w * bf2f(r[j].y);
            az += w * bf2f(r[j].z); aw += w * bf2f(r[j].w);
        }
    }
    for (; p + 4 <= p1; p += 4) {
        int2 e[4]; short4 r[4];
        #pragma unroll
        for (int j = 0; j < 4; ++j) e[j] = er[p + j];
        #pragma unroll
        for (int j = 0; j < 4; ++j) r[j] = *(const short4*)(h1h + (size_t)e[j].x * HID + lo4);
        #pragma unroll
        for (int j = 0; j < 4; ++j) {
            float w = __int_as_float(e[j].y);
            ax += w * bf2f(r[j].x); ay += w * bf2f(r[j].y);
            az += w * bf2f(r[j].z); aw += w * bf2f(r[j].w);
        }
    }
    for (; p < p1; ++p) {
        int2 e0 = er[p];
        float w0 = __int_as_float(e0.y);
        short4 r0 = *(const short4*)(h1h + (size_t)e0.x * HID + lo4);
        ax += w0 * bf2f(r0.x); ay += w0 * bf2f(r0.y);
        az += w0 * bf2f(r0.z); aw += w0 * bf2f(r0.w);
    }

    float a[4] = {ax, ay, az, aw};
    short hv[4], lv[4];
    #pragma unroll
    for (int i = 0; i < 4; ++i) {
        hv[i] = f2bf(a[i]);
        lv[i] = f2bf(a[i] - bf2f(hv[i]));
    }
    size_t base = (size_t)n * HID + lo4;
    *(short4*)&ahh[base] = make_short4(hv[0], hv[1], hv[2], hv[3]);
    *(short4*)&ahl[base] = make_short4(lv[0], lv[1], lv[2], lv[3]);
}

// ---------------- MFMA GEMM with fused bias+ReLU epilogue ----------------
// C[M,256] = relu(A[M,K] * W[256,K]^T + bias). Split-bf16 3-product.
// 64x64 tile, 4 waves each 32x32 (2x2 MFMA 16x16x32), BK=64, LDS-staged,
// register prefetch, XCD-affinity swizzle (4 nt-siblings share an XCD's L2).
// mode 0: store bf16-hi to Cbf; mode 1: store fp32 to Cf.

#define LDS_STRIDE 72

__global__ __launch_bounds__(256) void gemm_split(const short* __restrict__ Ah,
                                                  const short* __restrict__ Al,
                                                  const short* __restrict__ Wh,
                                                  const short* __restrict__ Wl,
                                                  const float* __restrict__ bias,
                                                  float* __restrict__ Cf,
                                                  short* __restrict__ Cbf,
                                                  int M, int Ks, int nsteps, int mode) {
    __shared__ short sAh[64 * LDS_STRIDE];
    __shared__ short sAl[64 * LDS_STRIDE];
    __shared__ short sWh[64 * LDS_STRIDE];
    __shared__ short sWl[64 * LDS_STRIDE];

    // swizzle: idx = group*32 + slot*8 + xcd  ->  mt = group*8 + xcd, nt = slot
    const int idx   = blockIdx.x;
    const int group = idx >> 5;
    const int xcd   = idx & 7;
    const int slot  = (idx >> 3) & 3;
    const int mt    = group * 8 + xcd;
    const int mtiles = (M + 63) >> 6;
    if (mt >= mtiles) return;
    const int bm = mt * 64;
    const int bn = slot * 64;

    const int tid  = threadIdx.x;
    const int lane = tid & 63;
    const int wv   = tid >> 6;
    const int l16  = lane & 15;
    const int quad = lane >> 4;
    const int wm   = (wv & 1) * 32;
    const int wn   = (wv >> 1) * 32;

    const int srow = tid >> 2;
    const int sseg = (tid & 3) * 16;
    int arow = bm + srow; if (arow >= M) arow = M - 1;
    const short* gAh = Ah + (size_t)arow * Ks;
    const short* gAl = Al + (size_t)arow * Ks;
    const short* gWh = Wh + (size_t)(bn + srow) * Ks;
    const short* gWl = Wl + (size_t)(bn + srow) * Ks;
    const int lds_off = srow * LDS_STRIDE + sseg;

    f32x4 acc00 = {0,0,0,0}, acc01 = {0,0,0,0}, acc10 = {0,0,0,0}, acc11 = {0,0,0,0};

    int4 pah0 = *(const int4*)(gAh + sseg), pah1 = *(const int4*)(gAh + sseg + 8);
    int4 pal0 = *(const int4*)(gAl + sseg), pal1 = *(const int4*)(gAl + sseg + 8);
    int4 pwh0 = *(const int4*)(gWh + sseg), pwh1 = *(const int4*)(gWh + sseg + 8);
    int4 pwl0 = *(const int4*)(gWl + sseg), pwl1 = *(const int4*)(gWl + sseg + 8);

    for (int ks = 0; ks < nsteps; ++ks) {
        *(int4*)&sAh[lds_off] = pah0; *(int4*)&sAh[lds_off + 8] = pah1;
        *(int4*)&sAl[lds_off] = pal0; *(int4*)&sAl[lds_off + 8] = pal1;
        *(int4*)&sWh[lds_off] = pwh0; *(int4*)&sWh[lds_off + 8] = pwh1;
        *(int4*)&sWl[lds_off] = pwl0; *(int4*)&sWl[lds_off + 8] = pwl1;
        __syncthreads();
        if (ks + 1 < nsteps) {
            int o = (ks + 1) * 64 + sseg;
            pah0 = *(const int4*)(gAh + o); pah1 = *(const int4*)(gAh + o + 8);
            pal0 = *(const int4*)(gAl + o); pal1 = *(const int4*)(gAl + o + 8);
            pwh0 = *(const int4*)(gWh + o); pwh1 = *(const int4*)(gWh + o + 8);
            pwl0 = *(const int4*)(gWl + o); pwl1 = *(const int4*)(gWl + o + 8);
        }
        #pragma unroll
        for (int o = 0; o < 2; ++o) {
            const int a0 = (wm + l16) * LDS_STRIDE + o * 32 + quad * 8;
            const int a1 = a0 + 16 * LDS_STRIDE;
            const int w0 = (wn + l16) * LDS_STRIDE + o * 32 + quad * 8;
            const int w1 = w0 + 16 * LDS_STRIDE;
            bf16x8 ah0 = *(const bf16x8*)&sAh[a0];
            bf16x8 ah1 = *(const bf16x8*)&sAh[a1];
            bf16x8 al0 = *(const bf16x8*)&sAl[a0];
            bf16x8 al1 = *(const bf16x8*)&sAl[a1];
            bf16x8 wh0 = *(const bf16x8*)&sWh[w0];
            bf16x8 wh1 = *(const bf16x8*)&sWh[w1];
            bf16x8 wl0 = *(const bf16x8*)&sWl[w0];
            bf16x8 wl1 = *(const bf16x8*)&sWl[w1];
            acc00 = __builtin_amdgcn_mfma_f32_16x16x32_bf16(ah0, wh0, acc00, 0, 0, 0);
            acc00 = __builtin_amdgcn_mfma_f32_16x16x32_bf16(ah0, wl0, acc00, 0, 0, 0);
            acc00 = __builtin_amdgcn_mfma_f32_16x16x32_bf16(al0, wh0, acc00, 0, 0, 0);
            acc01 = __builtin_amdgcn_mfma_f32_16x16x32_bf16(ah0, wh1, acc01, 0, 0, 0);
            acc01 = __builtin_amdgcn_mfma_f32_16x16x32_bf16(ah0, wl1, acc01, 0, 0, 0);
            acc01 = __builtin_amdgcn_mfma_f32_16x16x32_bf16(al0, wh1, acc01, 0, 0, 0);
            acc10 = __builtin_amdgcn_mfma_f32_16x16x32_bf16(ah1, wh0, acc10, 0, 0, 0);
            acc10 = __builtin_amdgcn_mfma_f32_16x16x32_bf16(ah1, wl0, acc10, 0, 0, 0);
            acc10 = __builtin_amdgcn_mfma_f32_16x16x32_bf16(al1, wh0, acc10, 0, 0, 0);
            acc11 = __builtin_amdgcn_mfma_f32_16x16x32_bf16(ah1, wh1, acc11, 0, 0, 0);
            acc11 = __builtin_amdgcn_mfma_f32_16x16x32_bf16(ah1, wl1, acc11, 0, 0, 0);
            acc11 = __builtin_amdgcn_mfma_f32_16x16x32_bf16(al1, wh1, acc11, 0, 0, 0);
        }
        __syncthreads();
    }

    const int colb = bn + wn + l16;
    const int rowb = bm + wm + quad * 4;
    const float b0 = bias[colb];
    const float b1 = bias[colb + 16];
    #pragma unroll
    for (int r = 0; r < 4; ++r) {
        int row = rowb + r;
        if (row < M) {
            float v0 = acc00[r] + b0; v0 = v0 > 0.f ? v0 : 0.f;
            float v1 = acc01[r] + b1; v1 = v1 > 0.f ? v1 : 0.f;
            if (mode == 0) {
                Cbf[(size_t)row * HID + colb]      = f2bf(v0);
                Cbf[(size_t)row * HID + colb + 16] = f2bf(v1);
            } else {
                Cf[(size_t)row * HID + colb]      = v0;
                Cf[(size_t)row * HID + colb + 16] = v1;
            }
        }
        int row2 = row + 16;
        if (row2 < M) {
            float v0 = acc10[r] + b0; v0 = v0 > 0.f ? v0 : 0.f;
            float v1 = acc11[r] + b1; v1 = v1 > 0.f ? v1 : 0.f;
            if (mode == 0) {
                Cbf[(size_t)row2 * HID + colb]      = f2bf(v0);
                Cbf[(size_t)row2 * HID + colb + 16] = f2bf(v1);
            } else {
                Cf[(size_t)row2 * HID + colb]      = v0;
                Cf[(size_t)row2 * HID + colb + 16] = v1;
            }
        }
    }
}

// ---------------- launch ----------------

extern "C" void kernel_launch(void* const* d_in, const int* in_sizes, int n_in,
                              void* d_out, int out_size, void* d_ws, size_t ws_size,
                              hipStream_t stream) {
    const float* x  = (const float*)d_in[0];
    const int*   ei = (const int*)d_in[1];
    const float* ew = (const float*)d_in[2];
    const float* W1 = (const float*)d_in[3];
    const float* b1 = (const float*)d_in[4];
    const float* W2 = (const float*)d_in[5];
    const float* b2 = (const float*)d_in[6];
    float* out = (float*)d_out;

    char* ws = (char*)d_ws;
    float* deg      = (float*)(ws);                 // 20000 f32 (becomes dinv)
    int*   counts   = (int*)(ws + 80000);           // 20000 i32
    int*   cursor   = (int*)(ws + 160000);          // 20000 i32
    int*   offs     = (int*)(ws + 240000);          // 20001 i32
    int*   bsum     = (int*)(ws + 320016);          // 20 i32 (pad to 320144)
    int2*  er       = (int2*)(ws + 320144);         // 320000 int2 -> 2880144
    // region A: agg_x split (2 x 20000x192 bf16 = 15.36MB), dead after gemm1;
    // reused for agg_h split (2 x 20000x256 bf16 = 20.48MB)
    short* axh      = (short*)(ws + 2880144);       // -> 10560144
    short* axl      = (short*)(ws + 10560144);      // -> 18240144
    short* ahh      = (short*)(ws + 2880144);       // -> 13120144
    short* ahl      = (short*)(ws + 13120144);      // -> 23360144
    short* h1h      = (short*)(ws + 23360144);      // 20000x256 bf16 -> 33600144
    short* w1h      = (short*)(ws + 33600144);      // 256x192 -> 33698448
    short* w1l      = (short*)(ws + 33698448);      // -> 33796752
    short* w2h      = (short*)(ws + 33796752);      // 256x256 -> 33927824
    short* w2l      = (short*)(ws + 33927824);      // -> 34058896
    short* xb       = (short*)(ws + 34058896);      // 20000x192 bf16 -> 41738896

    hipMemsetAsync(d_ws, 0, 240000, stream);        // deg, counts, cursor

    const int TB = 256;
    prep_all<<<N_NODES + 512 + (N_EDGES + 255) / 256, 256, 0, stream>>>(
        x, xb, W1, W2, w1h, w1l, w2h, w2l, ei, ew, deg, counts);
    scan_part<<<20, 1024, 0, stream>>>(counts, offs, bsum, deg, N_NODES);
    scan_add<<<20, 1024, 0, stream>>>(bsum, offs, N_NODES);
    scatter_edges<<<(N_EDGES + TB - 1) / TB, TB, 0, stream>>>(ei, ew, deg, offs, cursor, er);

    const int mtiles = (N_NODES + 63) / 64;          // 313
    const int gemm_grid = ((mtiles + 7) / 8) * 32;   // 1280
    // layer 1: Agg(bf16 xb) -> split; GEMM(+b1, ReLU) -> h1 bf16-hi
    agg_x_split<<<N_NODES / 4, 256, 0, stream>>>(xb, deg, offs, er, axh, axl);
    gemm_split<<<gemm_grid, 256, 0, stream>>>(axh, axl, w1h, w1l, b1, nullptr, h1h,
                                              N_NODES, K1P, 3, 0);
    // layer 2: Agg(bf16 h1) -> split; GEMM(+b2, ReLU) -> out fp32
    agg_h_split<<<N_NODES / 4, 256, 0, stream>>>(h1h, deg, offs, er, ahh, ahl);
    gemm_split<<<gemm_grid, 256, 0, stream>>>(ahh, ahl, w2h, w2l, b2, out, nullptr,
                                              N_NODES, HID, 4, 1);
}

// Round 13
// 209.707 us; speedup vs baseline: 1.2452x; 1.0492x over previous
//
#include <hip/hip_runtime.h>

#define N_NODES 20000
#define N_EDGES 320000
#define IN_F    168
#define HID     256
#define K1P     192   // GEMM-1 K (IN_F zero-padded to multiple of 64)
#define XS      192   // xb row stride in shorts (384B, 128B-aligned)
#define NF4     42    // IN_F / 4

typedef __attribute__((ext_vector_type(8))) short bf16x8;
typedef __attribute__((ext_vector_type(4))) float f32x4;

__device__ __forceinline__ short f2bf(float f) {
    union { float f; unsigned u; } v; v.f = f;
    unsigned r = v.u + 0x7FFFu + ((v.u >> 16) & 1u);
    return (short)(r >> 16);
}
__device__ __forceinline__ float bf2f(short s) {
    union { unsigned u; float f; } v; v.u = ((unsigned)(unsigned short)s) << 16;
    return v.f;
}

// ---------------- fused prep: x->bf16 (192-padded), W splits, edge deg/count ----

__global__ void prep_all(const float* __restrict__ x, short* __restrict__ xb,
                         const float* __restrict__ W1, const float* __restrict__ W2,
                         short* __restrict__ w1h, short* __restrict__ w1l,
                         short* __restrict__ w2h, short* __restrict__ w2l,
                         const int* __restrict__ ei, const float* __restrict__ ew,
                         float* __restrict__ deg, int* __restrict__ counts) {
    int b = blockIdx.x;
    int k = threadIdx.x;
    if (b < N_NODES) {
        if (k >= XS) return;
        float v = (k < IN_F) ? x[(size_t)b * IN_F + k] : 0.f;
        xb[(size_t)b * XS + k] = f2bf(v);
        return;
    }
    b -= N_NODES;
    if (b < 256) {
        if (k >= K1P) return;
        float v = (k < IN_F) ? W1[(size_t)b * IN_F + k] : 0.f;
        short h = f2bf(v);
        w1h[(size_t)b * K1P + k] = h;
        w1l[(size_t)b * K1P + k] = f2bf(v - bf2f(h));
        return;
    }
    if (b < 512) {
        int r = b - 256;
        float v = W2[(size_t)r * HID + k];
        short h = f2bf(v);
        w2h[(size_t)r * HID + k] = h;
        w2l[(size_t)r * HID + k] = f2bf(v - bf2f(h));
        return;
    }
    int e = (b - 512) * 256 + k;
    if (e < N_EDGES) {
        int d = ei[N_EDGES + e];
        atomicAdd(&deg[d], ew[e]);
        atomicAdd(&counts[d], 1);
    }
}

// ---------------- scan (2-kernel) + scatter ----------------

__global__ __launch_bounds__(1024) void scan_part(const int* __restrict__ counts,
                                                  int* __restrict__ offs,
                                                  int* __restrict__ bsum,
                                                  float* __restrict__ deg, int n) {
    int tid  = threadIdx.x;
    int lane = tid & 63;
    int wv   = tid >> 6;
    int i = blockIdx.x * 1024 + tid;
    if (i < n) deg[i] = rsqrtf(deg[i] + 1.0f);     // self-loop weight 1.0
    __shared__ int wsum[16];
    int v = (i < n) ? counts[i] : 0;
    int incl = v;
    #pragma unroll
    for (int d = 1; d < 64; d <<= 1) {
        int t = __shfl_up(incl, d);
        if (lane >= d) incl += t;
    }
    if (lane == 63) wsum[wv] = incl;
    __syncthreads();
    if (wv == 0) {
        int w = (lane < 16) ? wsum[lane] : 0;
        int winc = w;
        #pragma unroll
        for (int d = 1; d < 16; d <<= 1) {
            int t = __shfl_up(winc, d);
            if (lane >= d) winc += t;
        }
        if (lane < 16) wsum[lane] = winc - w;
    }
    __syncthreads();
    if (i < n) offs[i] = wsum[wv] + incl - v;
    if (tid == 1023) bsum[blockIdx.x] = wsum[15] + incl;
}

__global__ __launch_bounds__(1024) void scan_add(const int* __restrict__ bsum,
                                                 int* __restrict__ offs, int n) {
    int i = blockIdx.x * 1024 + threadIdx.x;
    int add = 0;
    for (int b = 0; b < (int)blockIdx.x; ++b) add += bsum[b];
    if (i < n) offs[i] += add;
    if (i == n) offs[n] = add + bsum[blockIdx.x];
}

// packed edge record: .x = src node, .y = norm as float bits
__global__ void scatter_edges(const int* __restrict__ ei, const float* __restrict__ ew,
                              const float* __restrict__ dinv, const int* __restrict__ offs,
                              int* __restrict__ cursor, int2* __restrict__ er) {
    int e = blockIdx.x * blockDim.x + threadIdx.x;
    if (e >= N_EDGES) return;
    int s = ei[e];
    int d = ei[N_EDGES + e];
    int pos = offs[d] + atomicAdd(&cursor[d], 1);
    float nm = dinv[s] * ew[e] * dinv[d];
    er[pos] = make_int2(s, __float_as_int(nm));
}

// ---------------- gathers (Agg BEFORE GEMM; emit bf16 A operand, hi only) ------

// layer 1: agg from bf16 xb rows (384B stride); lanes 0..41 own short4.
__global__ __launch_bounds__(256) void agg_x(const short* __restrict__ xb,
                                             const float* __restrict__ dinv,
                                             const int* __restrict__ offs,
                                             const int2* __restrict__ er,
                                             short* __restrict__ ax) {
    int wave = threadIdx.x >> 6;
    int lane = threadIdx.x & 63;
    int n = blockIdx.x * 4 + wave;
    bool act = lane < NF4;
    int lo4 = act ? lane * 4 : 0;                  // inactive lanes read row start (safe)
    float di = dinv[n];
    float sw = di * di;
    short4 sv = *(const short4*)(xb + (size_t)n * XS + lo4);
    float a0 = sw * bf2f(sv.x), a1 = sw * bf2f(sv.y);
    float a2 = sw * bf2f(sv.z), a3 = sw * bf2f(sv.w);

    int p0 = offs[n], p1 = offs[n + 1];
    int p = p0;
    for (; p + 8 <= p1; p += 8) {
        int2 e[8]; short4 r[8];
        #pragma unroll
        for (int j = 0; j < 8; ++j) e[j] = er[p + j];
        #pragma unroll
        for (int j = 0; j < 8; ++j) r[j] = *(const short4*)(xb + (size_t)e[j].x * XS + lo4);
        #pragma unroll
        for (int j = 0; j < 8; ++j) {
            float w = __int_as_float(e[j].y);
            a0 += w * bf2f(r[j].x); a1 += w * bf2f(r[j].y);
            a2 += w * bf2f(r[j].z); a3 += w * bf2f(r[j].w);
        }
    }
    for (; p + 4 <= p1; p += 4) {
        int2 e[4]; short4 r[4];
        #pragma unroll
        for (int j = 0; j < 4; ++j) e[j] = er[p + j];
        #pragma unroll
        for (int j = 0; j < 4; ++j) r[j] = *(const short4*)(xb + (size_t)e[j].x * XS + lo4);
        #pragma unroll
        for (int j = 0; j < 4; ++j) {
            float w = __int_as_float(e[j].y);
            a0 += w * bf2f(r[j].x); a1 += w * bf2f(r[j].y);
            a2 += w * bf2f(r[j].z); a3 += w * bf2f(r[j].w);
        }
    }
    for (; p < p1; ++p) {
        int2 e0 = er[p];
        float w0 = __int_as_float(e0.y);
        short4 r0 = *(const short4*)(xb + (size_t)e0.x * XS + lo4);
        a0 += w0 * bf2f(r0.x); a1 += w0 * bf2f(r0.y);
        a2 += w0 * bf2f(r0.z); a3 += w0 * bf2f(r0.w);
    }

    size_t base = (size_t)n * K1P + lane * 4;
    if (act) {
        *(short4*)&ax[base] = make_short4(f2bf(a0), f2bf(a1), f2bf(a2), f2bf(a3));
    } else if (lane < 48) {                        // zero pad cols 168..191
        *(short4*)&ax[base] = make_short4(0, 0, 0, 0);
    }
}

// layer 2: agg from bf16 h1 rows (512B); one short4 per lane; 8-deep ILP.
__global__ __launch_bounds__(256) void agg_h(const short* __restrict__ h1h,
                                             const float* __restrict__ dinv,
                                             const int* __restrict__ offs,
                                             const int2* __restrict__ er,
                                             short* __restrict__ ah) {
    int wave = threadIdx.x >> 6;
    int lane = threadIdx.x & 63;
    int n = blockIdx.x * 4 + wave;
    int lo4 = lane * 4;
    float di = dinv[n];
    float sw = di * di;
    short4 sv = *(const short4*)(h1h + (size_t)n * HID + lo4);
    float a0 = sw * bf2f(sv.x), a1 = sw * bf2f(sv.y);
    float a2 = sw * bf2f(sv.z), a3 = sw * bf2f(sv.w);

    int p0 = offs[n], p1 = offs[n + 1];
    int p = p0;
    for (; p + 8 <= p1; p += 8) {
        int2 e[8]; short4 r[8];
        #pragma unroll
        for (int j = 0; j < 8; ++j) e[j] = er[p + j];
        #pragma unroll
        for (int j = 0; j < 8; ++j) r[j] = *(const short4*)(h1h + (size_t)e[j].x * HID + lo4);
        #pragma unroll
        for (int j = 0; j < 8; ++j) {
            float w = __int_as_float(e[j].y);
            a0 += w * bf2f(r[j].x); a1 += w * bf2f(r[j].y);
            a2 += w * bf2f(r[j].z); a3 += w * bf2f(r[j].w);
        }
    }
    for (; p + 4 <= p1; p += 4) {
        int2 e[4]; short4 r[4];
        #pragma unroll
        for (int j = 0; j < 4; ++j) e[j] = er[p + j];
        #pragma unroll
        for (int j = 0; j < 4; ++j) r[j] = *(const short4*)(h1h + (size_t)e[j].x * HID + lo4);
        #pragma unroll
        for (int j = 0; j < 4; ++j) {
            float w = __int_as_float(e[j].y);
            a0 += w * bf2f(r[j].x); a1 += w * bf2f(r[j].y);
            a2 += w * bf2f(r[j].z); a3 += w * bf2f(r[j].w);
        }
    }
    for (; p < p1; ++p) {
        int2 e0 = er[p];
        float w0 = __int_as_float(e0.y);
        short4 r0 = *(const short4*)(h1h + (size_t)e0.x * HID + lo4);
        a0 += w0 * bf2f(r0.x); a1 += w0 * bf2f(r0.y);
        a2 += w0 * bf2f(r0.z); a3 += w0 * bf2f(r0.w);
    }

    size_t base = (size_t)n * HID + lo4;
    *(short4*)&ah[base] = make_short4(f2bf(a0), f2bf(a1), f2bf(a2), f2bf(a3));
}

// ---------------- MFMA GEMM (2-product) with fused bias+ReLU epilogue ----------
// C[M,256] = relu(A[M,K] * W[256,K]^T + bias), W split-bf16: Ah·Wh + Ah·Wl.
// A-side residual dropped: its term is ~2e-4 (rms(Al)·rms(W)·sqrtK), an order
// below the 4.4e-3 threshold; W-side lo is precomputed once and L2-resident.
// 64x64 tile, 4 waves each 32x32 (2x2 MFMA 16x16x32), BK=64, LDS-staged,
// register prefetch, XCD-affinity swizzle. mode 0: bf16-hi out; mode 1: fp32 out.

#define LDS_STRIDE 72

__global__ __launch_bounds__(256) void gemm_w2(const short* __restrict__ Ah,
                                               const short* __restrict__ Wh,
                                               const short* __restrict__ Wl,
                                               const float* __restrict__ bias,
                                               float* __restrict__ Cf,
                                               short* __restrict__ Cbf,
                                               int M, int Ks, int nsteps, int mode) {
    __shared__ short sAh[64 * LDS_STRIDE];
    __shared__ short sWh[64 * LDS_STRIDE];
    __shared__ short sWl[64 * LDS_STRIDE];

    // swizzle: idx = group*32 + slot*8 + xcd  ->  mt = group*8 + xcd, nt = slot
    const int idx   = blockIdx.x;
    const int group = idx >> 5;
    const int xcd   = idx & 7;
    const int slot  = (idx >> 3) & 3;
    const int mt    = group * 8 + xcd;
    const int mtiles = (M + 63) >> 6;
    if (mt >= mtiles) return;
    const int bm = mt * 64;
    const int bn = slot * 64;

    const int tid  = threadIdx.x;
    const int lane = tid & 63;
    const int wv   = tid >> 6;
    const int l16  = lane & 15;
    const int quad = lane >> 4;
    const int wm   = (wv & 1) * 32;
    const int wn   = (wv >> 1) * 32;

    const int srow = tid >> 2;
    const int sseg = (tid & 3) * 16;
    int arow = bm + srow; if (arow >= M) arow = M - 1;
    const short* gAh = Ah + (size_t)arow * Ks;
    const short* gWh = Wh + (size_t)(bn + srow) * Ks;
    const short* gWl = Wl + (size_t)(bn + srow) * Ks;
    const int lds_off = srow * LDS_STRIDE + sseg;

    f32x4 acc00 = {0,0,0,0}, acc01 = {0,0,0,0}, acc10 = {0,0,0,0}, acc11 = {0,0,0,0};

    int4 pah0 = *(const int4*)(gAh + sseg), pah1 = *(const int4*)(gAh + sseg + 8);
    int4 pwh0 = *(const int4*)(gWh + sseg), pwh1 = *(const int4*)(gWh + sseg + 8);
    int4 pwl0 = *(const int4*)(gWl + sseg), pwl1 = *(const int4*)(gWl + sseg + 8);

    for (int ks = 0; ks < nsteps; ++ks) {
        *(int4*)&sAh[lds_off] = pah0; *(int4*)&sAh[lds_off + 8] = pah1;
        *(int4*)&sWh[lds_off] = pwh0; *(int4*)&sWh[lds_off + 8] = pwh1;
        *(int4*)&sWl[lds_off] = pwl0; *(int4*)&sWl[lds_off + 8] = pwl1;
        __syncthreads();
        if (ks + 1 < nsteps) {
            int o = (ks + 1) * 64 + sseg;
            pah0 = *(const int4*)(gAh + o); pah1 = *(const int4*)(gAh + o + 8);
            pwh0 = *(const int4*)(gWh + o); pwh1 = *(const int4*)(gWh + o + 8);
            pwl0 = *(const int4*)(gWl + o); pwl1 = *(const int4*)(gWl + o + 8);
        }
        #pragma unroll
        for (int o = 0; o < 2; ++o) {
            const int a0 = (wm + l16) * LDS_STRIDE + o * 32 + quad * 8;
            const int a1 = a0 + 16 * LDS_STRIDE;
            const int w0 = (wn + l16) * LDS_STRIDE + o * 32 + quad * 8;
            const int w1 = w0 + 16 * LDS_STRIDE;
            bf16x8 ah0 = *(const bf16x8*)&sAh[a0];
            bf16x8 ah1 = *(const bf16x8*)&sAh[a1];
            bf16x8 wh0 = *(const bf16x8*)&sWh[w0];
            bf16x8 wh1 = *(const bf16x8*)&sWh[w1];
            bf16x8 wl0 = *(const bf16x8*)&sWl[w0];
            bf16x8 wl1 = *(const bf16x8*)&sWl[w1];
            acc00 = __builtin_amdgcn_mfma_f32_16x16x32_bf16(ah0, wh0, acc00, 0, 0, 0);
            acc00 = __builtin_amdgcn_mfma_f32_16x16x32_bf16(ah0, wl0, acc00, 0, 0, 0);
            acc01 = __builtin_amdgcn_mfma_f32_16x16x32_bf16(ah0, wh1, acc01, 0, 0, 0);
            acc01 = __builtin_amdgcn_mfma_f32_16x16x32_bf16(ah0, wl1, acc01, 0, 0, 0);
            acc10 = __builtin_amdgcn_mfma_f32_16x16x32_bf16(ah1, wh0, acc10, 0, 0, 0);
            acc10 = __builtin_amdgcn_mfma_f32_16x16x32_bf16(ah1, wl0, acc10, 0, 0, 0);
            acc11 = __builtin_amdgcn_mfma_f32_16x16x32_bf16(ah1, wh1, acc11, 0, 0, 0);
            acc11 = __builtin_amdgcn_mfma_f32_16x16x32_bf16(ah1, wl1, acc11, 0, 0, 0);
        }
        __syncthreads();
    }

    const int colb = bn + wn + l16;
    const int rowb = bm + wm + quad * 4;
    const float b0 = bias[colb];
    const float b1 = bias[colb + 16];
    #pragma unroll
    for (int r = 0; r < 4; ++r) {
        int row = rowb + r;
        if (row < M) {
            float v0 = acc00[r] + b0; v0 = v0 > 0.f ? v0 : 0.f;
            float v1 = acc01[r] + b1; v1 = v1 > 0.f ? v1 : 0.f;
            if (mode == 0) {
                Cbf[(size_t)row * HID + colb]      = f2bf(v0);
                Cbf[(size_t)row * HID + colb + 16] = f2bf(v1);
            } else {
                Cf[(size_t)row * HID + colb]      = v0;
                Cf[(size_t)row * HID + colb + 16] = v1;
            }
        }
        int row2 = row + 16;
        if (row2 < M) {
            float v0 = acc10[r] + b0; v0 = v0 > 0.f ? v0 : 0.f;
            float v1 = acc11[r] + b1; v1 = v1 > 0.f ? v1 : 0.f;
            if (mode == 0) {
                Cbf[(size_t)row2 * HID + colb]      = f2bf(v0);
                Cbf[(size_t)row2 * HID + colb + 16] = f2bf(v1);
            } else {
                Cf[(size_t)row2 * HID + colb]      = v0;
                Cf[(size_t)row2 * HID + colb + 16] = v1;
            }
        }
    }
}

// ---------------- launch ----------------

extern "C" void kernel_launch(void* const* d_in, const int* in_sizes, int n_in,
                              void* d_out, int out_size, void* d_ws, size_t ws_size,
                              hipStream_t stream) {
    const float* x  = (const float*)d_in[0];
    const int*   ei = (const int*)d_in[1];
    const float* ew = (const float*)d_in[2];
    const float* W1 = (const float*)d_in[3];
    const float* b1 = (const float*)d_in[4];
    const float* W2 = (const float*)d_in[5];
    const float* b2 = (const float*)d_in[6];
    float* out = (float*)d_out;

    char* ws = (char*)d_ws;
    float* deg      = (float*)(ws);                 // 20000 f32 (becomes dinv)
    int*   counts   = (int*)(ws + 80000);           // 20000 i32
    int*   cursor   = (int*)(ws + 160000);          // 20000 i32
    int*   offs     = (int*)(ws + 240000);          // 20001 i32
    int*   bsum     = (int*)(ws + 320016);          // 20 i32 (pad to 320144)
    int2*  er       = (int2*)(ws + 320144);         // 320000 int2 -> 2880144
    // region A: ax (20000x192 bf16, 7.68MB) dead after gemm1; reused for ah
    short* ax       = (short*)(ws + 2880144);       // -> 10560144
    short* ah       = (short*)(ws + 2880144);       // 20000x256 -> 13120144
    short* h1h      = (short*)(ws + 23360144);      // 20000x256 bf16 -> 33600144
    short* w1h      = (short*)(ws + 33600144);      // 256x192 -> 33698448
    short* w1l      = (short*)(ws + 33698448);      // -> 33796752
    short* w2h      = (short*)(ws + 33796752);      // 256x256 -> 33927824
    short* w2l      = (short*)(ws + 33927824);      // -> 34058896
    short* xb       = (short*)(ws + 34058896);      // 20000x192 bf16 -> 41738896

    hipMemsetAsync(d_ws, 0, 240000, stream);        // deg, counts, cursor

    const int TB = 256;
    prep_all<<<N_NODES + 512 + (N_EDGES + 255) / 256, 256, 0, stream>>>(
        x, xb, W1, W2, w1h, w1l, w2h, w2l, ei, ew, deg, counts);
    scan_part<<<20, 1024, 0, stream>>>(counts, offs, bsum, deg, N_NODES);
    scan_add<<<20, 1024, 0, stream>>>(bsum, offs, N_NODES);
    scatter_edges<<<(N_EDGES + TB - 1) / TB, TB, 0, stream>>>(ei, ew, deg, offs, cursor, er);

    const int mtiles = (N_NODES + 63) / 64;          // 313
    const int gemm_grid = ((mtiles + 7) / 8) * 32;   // 1280
    // layer 1: Agg(bf16 xb) -> bf16; GEMM(+b1, ReLU) -> h1 bf16
    agg_x<<<N_NODES / 4, 256, 0, stream>>>(xb, deg, offs, er, ax);
    gemm_w2<<<gemm_grid, 256, 0, stream>>>(ax, w1h, w1l, b1, nullptr, h1h,
                                           N_NODES, K1P, 3, 0);
    // layer 2: Agg(bf16 h1) -> bf16; GEMM(+b2, ReLU) -> out fp32
    agg_h<<<N_NODES / 4, 256, 0, stream>>>(h1h, deg, offs, er, ah);
    gemm_w2<<<gemm_grid, 256, 0, stream>>>(ah, w2h, w2l, b2, out, nullptr,
                                           N_NODES, HID, 4, 1);
}

// Round 14
// 201.090 us; speedup vs baseline: 1.2986x; 1.0429x over previous
//
#include <hip/hip_runtime.h>

#define N_NODES 20000
#define N_EDGES 320000
#define IN_F    168
#define HID     256
#define K1P     192   // GEMM-1 K (IN_F zero-padded to multiple of 64)
#define XS      192   // xb row stride in shorts (384B, 128B-aligned)
#define NF4     42    // IN_F / 4

typedef __attribute__((ext_vector_type(8))) short bf16x8;
typedef __attribute__((ext_vector_type(4))) float f32x4;

__device__ __forceinline__ short f2bf(float f) {
    union { float f; unsigned u; } v; v.f = f;
    unsigned r = v.u + 0x7FFFu + ((v.u >> 16) & 1u);
    return (short)(r >> 16);
}
__device__ __forceinline__ float bf2f(short s) {
    union { unsigned u; float f; } v; v.u = ((unsigned)(unsigned short)s) << 16;
    return v.f;
}

// ---------------- fused prep: x->bf16 (192-padded), W->bf16, edge deg/count ----

__global__ void prep_all(const float* __restrict__ x, short* __restrict__ xb,
                         const float* __restrict__ W1, const float* __restrict__ W2,
                         short* __restrict__ w1b, short* __restrict__ w2b,
                         const int* __restrict__ ei, const float* __restrict__ ew,
                         float* __restrict__ deg, int* __restrict__ counts) {
    int b = blockIdx.x;
    int k = threadIdx.x;
    if (b < N_NODES) {
        if (k >= XS) return;
        float v = (k < IN_F) ? x[(size_t)b * IN_F + k] : 0.f;
        xb[(size_t)b * XS + k] = f2bf(v);
        return;
    }
    b -= N_NODES;
    if (b < 256) {
        if (k >= K1P) return;
        float v = (k < IN_F) ? W1[(size_t)b * IN_F + k] : 0.f;
        w1b[(size_t)b * K1P + k] = f2bf(v);
        return;
    }
    if (b < 512) {
        int r = b - 256;
        w2b[(size_t)r * HID + k] = f2bf(W2[(size_t)r * HID + k]);
        return;
    }
    int e = (b - 512) * 256 + k;
    if (e < N_EDGES) {
        int d = ei[N_EDGES + e];
        atomicAdd(&deg[d], ew[e]);
        atomicAdd(&counts[d], 1);
    }
}

// ---------------- scan (2-kernel) + scatter ----------------

__global__ __launch_bounds__(1024) void scan_part(const int* __restrict__ counts,
                                                  int* __restrict__ offs,
                                                  int* __restrict__ bsum,
                                                  float* __restrict__ deg, int n) {
    int tid  = threadIdx.x;
    int lane = tid & 63;
    int wv   = tid >> 6;
    int i = blockIdx.x * 1024 + tid;
    if (i < n) deg[i] = rsqrtf(deg[i] + 1.0f);     // self-loop weight 1.0
    __shared__ int wsum[16];
    int v = (i < n) ? counts[i] : 0;
    int incl = v;
    #pragma unroll
    for (int d = 1; d < 64; d <<= 1) {
        int t = __shfl_up(incl, d);
        if (lane >= d) incl += t;
    }
    if (lane == 63) wsum[wv] = incl;
    __syncthreads();
    if (wv == 0) {
        int w = (lane < 16) ? wsum[lane] : 0;
        int winc = w;
        #pragma unroll
        for (int d = 1; d < 16; d <<= 1) {
            int t = __shfl_up(winc, d);
            if (lane >= d) winc += t;
        }
        if (lane < 16) wsum[lane] = winc - w;
    }
    __syncthreads();
    if (i < n) offs[i] = wsum[wv] + incl - v;
    if (tid == 1023) bsum[blockIdx.x] = wsum[15] + incl;
}

__global__ __launch_bounds__(1024) void scan_add(const int* __restrict__ bsum,
                                                 int* __restrict__ offs, int n) {
    int i = blockIdx.x * 1024 + threadIdx.x;
    int add = 0;
    for (int b = 0; b < (int)blockIdx.x; ++b) add += bsum[b];
    if (i < n) offs[i] += add;
    if (i == n) offs[n] = add + bsum[blockIdx.x];
}

// packed edge record: .x = src node, .y = norm as float bits
__global__ void scatter_edges(const int* __restrict__ ei, const float* __restrict__ ew,
                              const float* __restrict__ dinv, const int* __restrict__ offs,
                              int* __restrict__ cursor, int2* __restrict__ er) {
    int e = blockIdx.x * blockDim.x + threadIdx.x;
    if (e >= N_EDGES) return;
    int s = ei[e];
    int d = ei[N_EDGES + e];
    int pos = offs[d] + atomicAdd(&cursor[d], 1);
    float nm = dinv[s] * ew[e] * dinv[d];
    er[pos] = make_int2(s, __float_as_int(nm));
}

// ---------------- gathers (Agg BEFORE GEMM; emit bf16 A operand) ----------------

// layer 1: agg from bf16 xb rows (384B stride); lanes 0..41 own short4.
__global__ __launch_bounds__(256) void agg_x(const short* __restrict__ xb,
                                             const float* __restrict__ dinv,
                                             const int* __restrict__ offs,
                                             const int2* __restrict__ er,
                                             short* __restrict__ ax) {
    int wave = threadIdx.x >> 6;
    int lane = threadIdx.x & 63;
    int n = blockIdx.x * 4 + wave;
    bool act = lane < NF4;
    int lo4 = act ? lane * 4 : 0;                  // inactive lanes read row start (safe)
    float di = dinv[n];
    float sw = di * di;
    short4 sv = *(const short4*)(xb + (size_t)n * XS + lo4);
    float a0 = sw * bf2f(sv.x), a1 = sw * bf2f(sv.y);
    float a2 = sw * bf2f(sv.z), a3 = sw * bf2f(sv.w);

    int p0 = offs[n], p1 = offs[n + 1];
    int p = p0;
    for (; p + 8 <= p1; p += 8) {
        int2 e[8]; short4 r[8];
        #pragma unroll
        for (int j = 0; j < 8; ++j) e[j] = er[p + j];
        #pragma unroll
        for (int j = 0; j < 8; ++j) r[j] = *(const short4*)(xb + (size_t)e[j].x * XS + lo4);
        #pragma unroll
        for (int j = 0; j < 8; ++j) {
            float w = __int_as_float(e[j].y);
            a0 += w * bf2f(r[j].x); a1 += w * bf2f(r[j].y);
            a2 += w * bf2f(r[j].z); a3 += w * bf2f(r[j].w);
        }
    }
    for (; p + 4 <= p1; p += 4) {
        int2 e[4]; short4 r[4];
        #pragma unroll
        for (int j = 0; j < 4; ++j) e[j] = er[p + j];
        #pragma unroll
        for (int j = 0; j < 4; ++j) r[j] = *(const short4*)(xb + (size_t)e[j].x * XS + lo4);
        #pragma unroll
        for (int j = 0; j < 4; ++j) {
            float w = __int_as_float(e[j].y);
            a0 += w * bf2f(r[j].x); a1 += w * bf2f(r[j].y);
            a2 += w * bf2f(r[j].z); a3 += w * bf2f(r[j].w);
        }
    }
    for (; p < p1; ++p) {
        int2 e0 = er[p];
        float w0 = __int_as_float(e0.y);
        short4 r0 = *(const short4*)(xb + (size_t)e0.x * XS + lo4);
        a0 += w0 * bf2f(r0.x); a1 += w0 * bf2f(r0.y);
        a2 += w0 * bf2f(r0.z); a3 += w0 * bf2f(r0.w);
    }

    size_t base = (size_t)n * K1P + lane * 4;
    if (act) {
        *(short4*)&ax[base] = make_short4(f2bf(a0), f2bf(a1), f2bf(a2), f2bf(a3));
    } else if (lane < 48) {                        // zero pad cols 168..191
        *(short4*)&ax[base] = make_short4(0, 0, 0, 0);
    }
}

// layer 2: agg from bf16 h1 rows (512B); one short4 per lane; 8-deep ILP.
__global__ __launch_bounds__(256) void agg_h(const short* __restrict__ h1h,
                                             const float* __restrict__ dinv,
                                             const int* __restrict__ offs,
                                             const int2* __restrict__ er,
                                             short* __restrict__ ah) {
    int wave = threadIdx.x >> 6;
    int lane = threadIdx.x & 63;
    int n = blockIdx.x * 4 + wave;
    int lo4 = lane * 4;
    float di = dinv[n];
    float sw = di * di;
    short4 sv = *(const short4*)(h1h + (size_t)n * HID + lo4);
    float a0 = sw * bf2f(sv.x), a1 = sw * bf2f(sv.y);
    float a2 = sw * bf2f(sv.z), a3 = sw * bf2f(sv.w);

    int p0 = offs[n], p1 = offs[n + 1];
    int p = p0;
    for (; p + 8 <= p1; p += 8) {
        int2 e[8]; short4 r[8];
        #pragma unroll
        for (int j = 0; j < 8; ++j) e[j] = er[p + j];
        #pragma unroll
        for (int j = 0; j < 8; ++j) r[j] = *(const short4*)(h1h + (size_t)e[j].x * HID + lo4);
        #pragma unroll
        for (int j = 0; j < 8; ++j) {
            float w = __int_as_float(e[j].y);
            a0 += w * bf2f(r[j].x); a1 += w * bf2f(r[j].y);
            a2 += w * bf2f(r[j].z); a3 += w * bf2f(r[j].w);
        }
    }
    for (; p + 4 <= p1; p += 4) {
        int2 e[4]; short4 r[4];
        #pragma unroll
        for (int j = 0; j < 4; ++j) e[j] = er[p + j];
        #pragma unroll
        for (int j = 0; j < 4; ++j) r[j] = *(const short4*)(h1h + (size_t)e[j].x * HID + lo4);
        #pragma unroll
        for (int j = 0; j < 4; ++j) {
            float w = __int_as_float(e[j].y);
            a0 += w * bf2f(r[j].x); a1 += w * bf2f(r[j].y);
            a2 += w * bf2f(r[j].z); a3 += w * bf2f(r[j].w);
        }
    }
    for (; p < p1; ++p) {
        int2 e0 = er[p];
        float w0 = __int_as_float(e0.y);
        short4 r0 = *(const short4*)(h1h + (size_t)e0.x * HID + lo4);
        a0 += w0 * bf2f(r0.x); a1 += w0 * bf2f(r0.y);
        a2 += w0 * bf2f(r0.z); a3 += w0 * bf2f(r0.w);
    }

    size_t base = (size_t)n * HID + lo4;
    *(short4*)&ah[base] = make_short4(f2bf(a0), f2bf(a1), f2bf(a2), f2bf(a3));
}

// ---------------- MFMA GEMM (pure bf16) with fused bias+ReLU epilogue ----------
// C[M,256] = relu(A[M,K] * W[256,K]^T + bias), A and W bf16 (RNE), fp32 MFMA acc.
// Error budget: W-quant term ~2.2e-4 rms / ~1.1e-3 max (K=256) — inside the
// 4.36e-3 threshold with the measured 9.8e-4 bf16-gather error. 64x64 tile,
// 4 waves each 32x32 (2x2 MFMA 16x16x32), BK=64, LDS-staged (18.4 KB ->
// 8 blocks/CU), register prefetch, XCD-affinity swizzle.
// mode 0: bf16 out; mode 1: fp32 out.

#define LDS_STRIDE 72

__global__ __launch_bounds__(256) void gemm_bf(const short* __restrict__ Ah,
                                               const short* __restrict__ Wh,
                                               const float* __restrict__ bias,
                                               float* __restrict__ Cf,
                                               short* __restrict__ Cbf,
                                               int M, int Ks, int nsteps, int mode) {
    __shared__ short sAh[64 * LDS_STRIDE];
    __shared__ short sWh[64 * LDS_STRIDE];

    // swizzle: idx = group*32 + slot*8 + xcd  ->  mt = group*8 + xcd, nt = slot
    const int idx   = blockIdx.x;
    const int group = idx >> 5;
    const int xcd   = idx & 7;
    const int slot  = (idx >> 3) & 3;
    const int mt    = group * 8 + xcd;
    const int mtiles = (M + 63) >> 6;
    if (mt >= mtiles) return;
    const int bm = mt * 64;
    const int bn = slot * 64;

    const int tid  = threadIdx.x;
    const int lane = tid & 63;
    const int wv   = tid >> 6;
    const int l16  = lane & 15;
    const int quad = lane >> 4;
    const int wm   = (wv & 1) * 32;
    const int wn   = (wv >> 1) * 32;

    const int srow = tid >> 2;
    const int sseg = (tid & 3) * 16;
    int arow = bm + srow; if (arow >= M) arow = M - 1;
    const short* gAh = Ah + (size_t)arow * Ks;
    const short* gWh = Wh + (size_t)(bn + srow) * Ks;
    const int lds_off = srow * LDS_STRIDE + sseg;

    f32x4 acc00 = {0,0,0,0}, acc01 = {0,0,0,0}, acc10 = {0,0,0,0}, acc11 = {0,0,0,0};

    int4 pah0 = *(const int4*)(gAh + sseg), pah1 = *(const int4*)(gAh + sseg + 8);
    int4 pwh0 = *(const int4*)(gWh + sseg), pwh1 = *(const int4*)(gWh + sseg + 8);

    for (int ks = 0; ks < nsteps; ++ks) {
        *(int4*)&sAh[lds_off] = pah0; *(int4*)&sAh[lds_off + 8] = pah1;
        *(int4*)&sWh[lds_off] = pwh0; *(int4*)&sWh[lds_off + 8] = pwh1;
        __syncthreads();
        if (ks + 1 < nsteps) {
            int o = (ks + 1) * 64 + sseg;
            pah0 = *(const int4*)(gAh + o); pah1 = *(const int4*)(gAh + o + 8);
            pwh0 = *(const int4*)(gWh + o); pwh1 = *(const int4*)(gWh + o + 8);
        }
        #pragma unroll
        for (int o = 0; o < 2; ++o) {
            const int a0 = (wm + l16) * LDS_STRIDE + o * 32 + quad * 8;
            const int a1 = a0 + 16 * LDS_STRIDE;
            const int w0 = (wn + l16) * LDS_STRIDE + o * 32 + quad * 8;
            const int w1 = w0 + 16 * LDS_STRIDE;
            bf16x8 ah0 = *(const bf16x8*)&sAh[a0];
            bf16x8 ah1 = *(const bf16x8*)&sAh[a1];
            bf16x8 wh0 = *(const bf16x8*)&sWh[w0];
            bf16x8 wh1 = *(const bf16x8*)&sWh[w1];
            acc00 = __builtin_amdgcn_mfma_f32_16x16x32_bf16(ah0, wh0, acc00, 0, 0, 0);
            acc01 = __builtin_amdgcn_mfma_f32_16x16x32_bf16(ah0, wh1, acc01, 0, 0, 0);
            acc10 = __builtin_amdgcn_mfma_f32_16x16x32_bf16(ah1, wh0, acc10, 0, 0, 0);
            acc11 = __builtin_amdgcn_mfma_f32_16x16x32_bf16(ah1, wh1, acc11, 0, 0, 0);
        }
        __syncthreads();
    }

    const int colb = bn + wn + l16;
    const int rowb = bm + wm + quad * 4;
    const float b0 = bias[colb];
    const float b1 = bias[colb + 16];
    #pragma unroll
    for (int r = 0; r < 4; ++r) {
        int row = rowb + r;
        if (row < M) {
            float v0 = acc00[r] + b0; v0 = v0 > 0.f ? v0 : 0.f;
            float v1 = acc01[r] + b1; v1 = v1 > 0.f ? v1 : 0.f;
            if (mode == 0) {
                Cbf[(size_t)row * HID + colb]      = f2bf(v0);
                Cbf[(size_t)row * HID + colb + 16] = f2bf(v1);
            } else {
                Cf[(size_t)row * HID + colb]      = v0;
                Cf[(size_t)row * HID + colb + 16] = v1;
            }
        }
        int row2 = row + 16;
        if (row2 < M) {
            float v0 = acc10[r] + b0; v0 = v0 > 0.f ? v0 : 0.f;
            float v1 = acc11[r] + b1; v1 = v1 > 0.f ? v1 : 0.f;
            if (mode == 0) {
                Cbf[(size_t)row2 * HID + colb]      = f2bf(v0);
                Cbf[(size_t)row2 * HID + colb + 16] = f2bf(v1);
            } else {
                Cf[(size_t)row2 * HID + colb]      = v0;
                Cf[(size_t)row2 * HID + colb + 16] = v1;
            }
        }
    }
}

// ---------------- launch ----------------

extern "C" void kernel_launch(void* const* d_in, const int* in_sizes, int n_in,
                              void* d_out, int out_size, void* d_ws, size_t ws_size,
                              hipStream_t stream) {
    const float* x  = (const float*)d_in[0];
    const int*   ei = (const int*)d_in[1];
    const float* ew = (const float*)d_in[2];
    const float* W1 = (const float*)d_in[3];
    const float* b1 = (const float*)d_in[4];
    const float* W2 = (const float*)d_in[5];
    const float* b2 = (const float*)d_in[6];
    float* out = (float*)d_out;

    char* ws = (char*)d_ws;
    float* deg      = (float*)(ws);                 // 20000 f32 (becomes dinv)
    int*   counts   = (int*)(ws + 80000);           // 20000 i32
    int*   cursor   = (int*)(ws + 160000);          // 20000 i32
    int*   offs     = (int*)(ws + 240000);          // 20001 i32
    int*   bsum     = (int*)(ws + 320016);          // 20 i32 (pad to 320144)
    int2*  er       = (int2*)(ws + 320144);         // 320000 int2 -> 2880144
    // region A: ax (20000x192 bf16, 7.68MB) dead after gemm1; reused for ah
    short* ax       = (short*)(ws + 2880144);       // -> 10560144
    short* ah       = (short*)(ws + 2880144);       // 20000x256 -> 13120144
    short* h1h      = (short*)(ws + 23360144);      // 20000x256 bf16 -> 33600144
    short* w1b      = (short*)(ws + 33600144);      // 256x192 -> 33698448
    short* w2b      = (short*)(ws + 33698448);      // 256x256 -> 33829520
    short* xb       = (short*)(ws + 34058896);      // 20000x192 bf16 -> 41738896

    hipMemsetAsync(d_ws, 0, 240000, stream);        // deg, counts, cursor

    const int TB = 256;
    prep_all<<<N_NODES + 512 + (N_EDGES + 255) / 256, 256, 0, stream>>>(
        x, xb, W1, W2, w1b, w2b, ei, ew, deg, counts);
    scan_part<<<20, 1024, 0, stream>>>(counts, offs, bsum, deg, N_NODES);
    scan_add<<<20, 1024, 0, stream>>>(bsum, offs, N_NODES);
    scatter_edges<<<(N_EDGES + TB - 1) / TB, TB, 0, stream>>>(ei, ew, deg, offs, cursor, er);

    const int mtiles = (N_NODES + 63) / 64;          // 313
    const int gemm_grid = ((mtiles + 7) / 8) * 32;   // 1280
    // layer 1: Agg(bf16 xb) -> bf16; GEMM(+b1, ReLU) -> h1 bf16
    agg_x<<<N_NODES / 4, 256, 0, stream>>>(xb, deg, offs, er, ax);
    gemm_bf<<<gemm_grid, 256, 0, stream>>>(ax, w1b, b1, nullptr, h1h,
                                           N_NODES, K1P, 3, 0);
    // layer 2: Agg(bf16 h1) -> bf16; GEMM(+b2, ReLU) -> out fp32
    agg_h<<<N_NODES / 4, 256, 0, stream>>>(h1h, deg, offs, er, ah);
    gemm_bf<<<gemm_grid, 256, 0, stream>>>(ah, w2b, b2, out, nullptr,
                                           N_NODES, HID, 4, 1);
}